// Round 4
// baseline (371.534 us; speedup 1.0000x reference)
//
#include <hip/hip_runtime.h>

// Problem: B=16, L=128, D=256, O=256
// out[b,i,o] = relu( sum_j adj[b,i,j] * sum_d (text[b,j,d]+dep[b,j,i,d]) * W[d,o] + bias[o] )
// Reassociated: S[b,i,d] = sum_j adj[b,i,j]*(text[b,j,d]+dep[b,j,i,d]); out = relu(S@W + b)
// Memory-bound on the one-shot 268 MB read of dep_embed. Floor ~43 us @ ~6.5 TB/s.
//
// R4: i-QUAD per block (512 thr / 8 waves), grid 512 = 2 blocks/CU = 16 waves/CU.
// Little's law says ~10 KB in flight/CU suffices -> occupancy not binding; DRAM
// run length is. Each j-iter now reads 4 KB contiguous dep (4 adjacent i rows),
// halving stream count; text/W reads amortize 4x. VGPR cap 128 for deep loads.

constexpr int Bc = 16, Lc = 128, Dc = 256, Oc = 256;

__global__ __launch_bounds__(512, 4)
void gc_fused(const float4* __restrict__ text4,   // [B,L,D/4]
              const float*  __restrict__ adj,     // [B,L,L]
              const float4* __restrict__ dep4,    // [B,L,L,D/4]
              const float4* __restrict__ weight4, // [D,O/4]
              const float4* __restrict__ bias4,   // [O/4]
              float4* __restrict__ out4)          // [B,L,O/4]
{
    const int b    = blockIdx.x >> 5;     // 512 blocks = 16 b x 32 i-quads
    const int i0   = (blockIdx.x & 31) * 4;
    const int t    = threadIdx.x;
    const int w    = t >> 6;              // wave id 0..7
    const int lane = t & 63;              // float4 lane over D (and O)

    __shared__ float s_adj[4][Lc];        // 2 KB : the four adj rows
    __shared__ float s_buf[8][4][Dc];     // 32 KB: per-wave partials (S, then out)
    __shared__ float s_S[4][Dc];          // 4 KB : reduced S rows

    // Stage adj rows i0..i0+3 (512 floats).
    {
        int row = t >> 7, col = t & (Lc - 1);
        s_adj[row][col] = adj[((size_t)b * Lc + i0 + row) * Lc + col];
    }
    __syncthreads();

    // Phase 1: wave w accumulates j in [16w, 16w+16) for all 4 i rows.
    float4 a0 = {0.f,0.f,0.f,0.f}, a1 = a0, a2 = a0, a3 = a0;
    const int j0 = w * 16;
    const float4* tb = text4 + (size_t)b * Lc * (Dc / 4) + lane;                     // text[b][j][lane]
    const float4* db = dep4  + ((size_t)b * Lc * Lc + (size_t)i0) * (Dc / 4) + lane;  // dep[b][j][i0][lane]
    #pragma unroll 4
    for (int jj = 0; jj < 16; ++jj) {
        const int j = j0 + jj;
        const float4* dp = db + (size_t)j * (size_t)Lc * (Dc / 4);
        float4 tx = tb[(size_t)j * (Dc / 4)];
        float4 d0 = dp[0 * (Dc / 4)];   // 4 KB contiguous run across the quad
        float4 d1 = dp[1 * (Dc / 4)];
        float4 d2 = dp[2 * (Dc / 4)];
        float4 d3 = dp[3 * (Dc / 4)];
        float aj0 = s_adj[0][j], aj1 = s_adj[1][j], aj2 = s_adj[2][j], aj3 = s_adj[3][j];
        a0.x = fmaf(aj0, tx.x + d0.x, a0.x); a0.y = fmaf(aj0, tx.y + d0.y, a0.y);
        a0.z = fmaf(aj0, tx.z + d0.z, a0.z); a0.w = fmaf(aj0, tx.w + d0.w, a0.w);
        a1.x = fmaf(aj1, tx.x + d1.x, a1.x); a1.y = fmaf(aj1, tx.y + d1.y, a1.y);
        a1.z = fmaf(aj1, tx.z + d1.z, a1.z); a1.w = fmaf(aj1, tx.w + d1.w, a1.w);
        a2.x = fmaf(aj2, tx.x + d2.x, a2.x); a2.y = fmaf(aj2, tx.y + d2.y, a2.y);
        a2.z = fmaf(aj2, tx.z + d2.z, a2.z); a2.w = fmaf(aj2, tx.w + d2.w, a2.w);
        a3.x = fmaf(aj3, tx.x + d3.x, a3.x); a3.y = fmaf(aj3, tx.y + d3.y, a3.y);
        a3.z = fmaf(aj3, tx.z + d3.z, a3.z); a3.w = fmaf(aj3, tx.w + d3.w, a3.w);
    }
    ((float4*)&s_buf[w][0][0])[lane] = a0;
    ((float4*)&s_buf[w][1][0])[lane] = a1;
    ((float4*)&s_buf[w][2][0])[lane] = a2;
    ((float4*)&s_buf[w][3][0])[lane] = a3;
    __syncthreads();

    // Reduce partial S across 8 waves: 512 threads cover 4x256 entries, 2 each.
    #pragma unroll
    for (int e = 0; e < 2; ++e) {
        const int idx = t + e * 512;
        const int ii = idx >> 8, d = idx & (Dc - 1);
        float s = 0.f;
        #pragma unroll
        for (int p = 0; p < 8; ++p) s += s_buf[p][ii][d];
        s_S[ii][d] = s;
    }
    __syncthreads();   // also guards s_buf reuse below

    // Phase 2: wave w sums d in [32w, 32w+32): one W row serves 4 output rows.
    float4 o0 = {0.f,0.f,0.f,0.f}, o1 = o0, o2 = o0, o3 = o0;
    #pragma unroll 8
    for (int k = 0; k < 32; ++k) {
        const int d = w * 32 + k;
        float4 wv = weight4[d * (Oc / 4) + lane]; // coalesced, L2-resident
        float s0 = s_S[0][d], s1 = s_S[1][d], s2 = s_S[2][d], s3 = s_S[3][d];
        o0.x = fmaf(s0, wv.x, o0.x); o0.y = fmaf(s0, wv.y, o0.y);
        o0.z = fmaf(s0, wv.z, o0.z); o0.w = fmaf(s0, wv.w, o0.w);
        o1.x = fmaf(s1, wv.x, o1.x); o1.y = fmaf(s1, wv.y, o1.y);
        o1.z = fmaf(s1, wv.z, o1.z); o1.w = fmaf(s1, wv.w, o1.w);
        o2.x = fmaf(s2, wv.x, o2.x); o2.y = fmaf(s2, wv.y, o2.y);
        o2.z = fmaf(s2, wv.z, o2.z); o2.w = fmaf(s2, wv.w, o2.w);
        o3.x = fmaf(s3, wv.x, o3.x); o3.y = fmaf(s3, wv.y, o3.y);
        o3.z = fmaf(s3, wv.z, o3.z); o3.w = fmaf(s3, wv.w, o3.w);
    }
    ((float4*)&s_buf[w][0][0])[lane] = o0;
    ((float4*)&s_buf[w][1][0])[lane] = o1;
    ((float4*)&s_buf[w][2][0])[lane] = o2;
    ((float4*)&s_buf[w][3][0])[lane] = o3;
    __syncthreads();

    // Final: 256 threads reduce 8 partial outputs, add bias, ReLU, store.
    if (t < 4 * 64) {
        const int ii = t >> 6, l = t & 63;
        float4 r = bias4[l];
        #pragma unroll
        for (int p = 0; p < 8; ++p) {
            float4 v = ((float4*)&s_buf[p][ii][0])[l];
            r.x += v.x; r.y += v.y; r.z += v.z; r.w += v.w;
        }
        r.x = fmaxf(r.x, 0.f);
        r.y = fmaxf(r.y, 0.f);
        r.z = fmaxf(r.z, 0.f);
        r.w = fmaxf(r.w, 0.f);
        out4[((size_t)b * Lc + i0 + ii) * (Oc / 4) + l] = r;
    }
}

extern "C" void kernel_launch(void* const* d_in, const int* in_sizes, int n_in,
                              void* d_out, int out_size, void* d_ws, size_t ws_size,
                              hipStream_t stream) {
    const float4* text4   = (const float4*)d_in[0]; // [16,128,256] f32
    const float*  adj     = (const float*) d_in[1]; // [16,128,128] f32
    const float4* dep4    = (const float4*)d_in[2]; // [16,128,128,256] f32
    const float4* weight4 = (const float4*)d_in[3]; // [256,256] f32
    const float4* bias4   = (const float4*)d_in[4]; // [256] f32
    float4*       out4    = (float4*)d_out;         // [16,128,256] f32

    dim3 grid(Bc * (Lc / 4));   // 512 blocks, one per (b, i-quad)
    dim3 block(512);
    gc_fused<<<grid, block, 0, stream>>>(text4, adj, dep4, weight4, bias4, out4);
}

// Round 5
// 351.563 us; speedup vs baseline: 1.0568x; 1.0568x over previous
//
#include <hip/hip_runtime.h>

// Problem: B=16, L=128, D=256, O=256
// out[b,i,o] = relu( sum_j adj[b,i,j] * sum_d (text[b,j,d]+dep[b,j,i,d]) * W[d,o] + bias[o] )
// Reassociated: S[b,i,d] = sum_j adj[b,i,j]*(text[b,j,d]+dep[b,j,i,d]); out = relu(S@W + b)
// Memory-bound on the one-shot 268 MB read of dep_embed. Floor ~43 us @ ~6.5 TB/s.
//
// R5 = R3 (best: i-pair / 512 thr / 4 blocks/CU / 32 waves/CU) + NON-TEMPORAL
// dep loads. dep is read-once; letting it allocate in L2 recycles each XCD's
// 4 MB every ~6 us and evicts the reused set (text 2 MB + adj 1 MB + W 256 KB),
// turning their L2 re-reads into HBM re-fetches. `nt` keeps them resident.
// Output store also non-temporal (write-once).

constexpr int Bc = 16, Lc = 128, Dc = 256, Oc = 256;

typedef float f4 __attribute__((ext_vector_type(4)));

__global__ __launch_bounds__(512, 8)
void gc_fused(const f4* __restrict__ text4,   // [B,L,D/4]
              const float* __restrict__ adj,  // [B,L,L]
              const f4* __restrict__ dep4,    // [B,L,L,D/4]
              const f4* __restrict__ weight4, // [D,O/4]
              const f4* __restrict__ bias4,   // [O/4]
              f4* __restrict__ out4)          // [B,L,O/4]
{
    const int b    = blockIdx.x >> 6;     // 1024 blocks = 16 b x 64 i-pairs
    const int i0   = (blockIdx.x & 63) * 2;
    const int t    = threadIdx.x;
    const int w    = t >> 6;              // wave id 0..7
    const int lane = t & 63;              // f4 lane over D (and O)

    __shared__ float s_adj[2][Lc];        // 1 KB : the two adj rows
    __shared__ f4    s_buf[8][2][Dc / 4]; // 16 KB: per-wave partials (S, then out)
    __shared__ float s_S[2][Dc];          // 2 KB : reduced S rows

    // Stage adj rows i0, i0+1 (256 floats).
    if (t < 2 * Lc) {
        int row = t >> 7, col = t & (Lc - 1);
        s_adj[row][col] = adj[((size_t)b * Lc + i0 + row) * Lc + col];
    }
    __syncthreads();

    // Phase 1: wave w accumulates j in [16w, 16w+16) for BOTH i rows.
    f4 a0 = {0.f, 0.f, 0.f, 0.f};
    f4 a1 = {0.f, 0.f, 0.f, 0.f};
    const int j0 = w * 16;
    const f4* tb = text4 + (size_t)b * Lc * (Dc / 4) + lane;                     // text[b][j][lane]
    const f4* db = dep4  + ((size_t)b * Lc * Lc + (size_t)i0) * (Dc / 4) + lane; // dep[b][j][i0][lane]
    #pragma unroll 4
    for (int jj = 0; jj < 16; ++jj) {
        const int j = j0 + jj;
        float aj0 = s_adj[0][j];
        float aj1 = s_adj[1][j];
        f4 tx = tb[(size_t)j * (Dc / 4)];                 // cached (reused across blocks)
        const f4* dp = db + (size_t)j * (size_t)Lc * (Dc / 4);
        f4 d0 = __builtin_nontemporal_load(dp);           // read-once: bypass L2 allocate
        f4 d1 = __builtin_nontemporal_load(dp + Dc / 4);  // adjacent i row, contiguous
        a0 += aj0 * (tx + d0);
        a1 += aj1 * (tx + d1);
    }
    s_buf[w][0][lane] = a0;
    s_buf[w][1][lane] = a1;
    __syncthreads();

    // Reduce partial S across 8 waves: thread t owns (i = t>>8, d = t&255).
    {
        const int ii = t >> 8, d = t & (Dc - 1);
        float s = 0.f;
        #pragma unroll
        for (int p = 0; p < 8; ++p) s += ((const float*)&s_buf[p][ii][0])[d];
        s_S[ii][d] = s;
    }
    __syncthreads();   // also guards s_buf reuse below

    // Phase 2: wave w sums d in [32w, 32w+32) of S[d]*W[d][o4=lane], both i.
    f4 o0 = {0.f, 0.f, 0.f, 0.f};
    f4 o1 = {0.f, 0.f, 0.f, 0.f};
    #pragma unroll 8
    for (int k = 0; k < 32; ++k) {
        const int d = w * 32 + k;
        f4 wv = weight4[d * (Oc / 4) + lane]; // coalesced, L2-resident (nt keeps it so)
        o0 += s_S[0][d] * wv;
        o1 += s_S[1][d] * wv;
    }
    s_buf[w][0][lane] = o0;
    s_buf[w][1][lane] = o1;
    __syncthreads();

    // Final: 128 threads reduce 8 partial outputs, add bias, ReLU, store (nt).
    if (t < 2 * 64) {
        const int ii = t >> 6, l = t & 63;
        f4 r = bias4[l];
        #pragma unroll
        for (int p = 0; p < 8; ++p) r += s_buf[p][ii][l];
        r.x = fmaxf(r.x, 0.f);
        r.y = fmaxf(r.y, 0.f);
        r.z = fmaxf(r.z, 0.f);
        r.w = fmaxf(r.w, 0.f);
        __builtin_nontemporal_store(r, &out4[((size_t)b * Lc + i0 + ii) * (Oc / 4) + l]);
    }
}

extern "C" void kernel_launch(void* const* d_in, const int* in_sizes, int n_in,
                              void* d_out, int out_size, void* d_ws, size_t ws_size,
                              hipStream_t stream) {
    const f4*    text4   = (const f4*)   d_in[0]; // [16,128,256] f32
    const float* adj     = (const float*)d_in[1]; // [16,128,128] f32
    const f4*    dep4    = (const f4*)   d_in[2]; // [16,128,128,256] f32
    const f4*    weight4 = (const f4*)   d_in[3]; // [256,256] f32
    const f4*    bias4   = (const f4*)   d_in[4]; // [256] f32
    f4*          out4    = (f4*)d_out;            // [16,128,256] f32

    dim3 grid(Bc * (Lc / 2));   // 1024 blocks, one per (b, i-pair)
    dim3 block(512);
    gc_fused<<<grid, block, 0, stream>>>(text4, adj, dep4, weight4, bias4, out4);
}